// Round 12
// baseline (103.476 us; speedup 1.0000x reference)
//
#include <hip/hip_runtime.h>
#include <hip/hip_bf16.h>

typedef float    f32x4  __attribute__((ext_vector_type(4)));
typedef short    bf16x8 __attribute__((ext_vector_type(8)));
typedef int      i32x4  __attribute__((ext_vector_type(4)));
typedef unsigned u32x2  __attribute__((ext_vector_type(2)));

#define Bsz  8192
#define Dsz  64
#define Hsz  128
#define Tsz  41
#define ROWS 16
#define NT   256

#define MFMA(a,b,c)  __builtin_amdgcn_mfma_f32_16x16x32_bf16((a),(b),(c),0,0,0)
#define MFMAI(a,b,c) __builtin_amdgcn_mfma_i32_16x16x64_i8((a),(b),(c),0,0,0)

__device__ __forceinline__ float fast_tanh(float x) {
    float ax = __builtin_fabsf(x);
    float e  = __expf(-2.0f * ax);
    float r  = (1.0f - e) * __builtin_amdgcn_rcpf(1.0f + e);
    return __builtin_copysignf(r, x);
}

__device__ __forceinline__ unsigned short bf2u(__hip_bfloat16 h) {
    union { __hip_bfloat16 b; unsigned short u; } v; v.b = h; return v.u;
}

union FragU { bf16x8 f; unsigned short h[8]; };

// split 8 f32 into hi/lo bf16 fragments (weights/init only)
__device__ __forceinline__ void split8(const float* x, bf16x8& hi, bf16x8& lo) {
    FragU H, L;
    #pragma unroll
    for (int i = 0; i < 8; ++i) {
        __hip_bfloat16 hb = __float2bfloat16(x[i]);
        H.h[i] = bf2u(hb);
        L.h[i] = bf2u(__float2bfloat16(x[i] - __bfloat162float(hb)));
    }
    hi = H.f; lo = L.f;
}

// split f32x4 -> packed H (2 dwords) and packed L bf16 (z-path, unchanged from R6)
__device__ __forceinline__ void splitq(const f32x4& x, u32x2& H, u32x2& L) {
    unsigned short h0 = bf2u(__float2bfloat16(x[0]));
    unsigned short h1 = bf2u(__float2bfloat16(x[1]));
    unsigned short h2 = bf2u(__float2bfloat16(x[2]));
    unsigned short h3 = bf2u(__float2bfloat16(x[3]));
    float f0 = __uint_as_float((unsigned)h0 << 16);
    float f1 = __uint_as_float((unsigned)h1 << 16);
    float f2 = __uint_as_float((unsigned)h2 << 16);
    float f3 = __uint_as_float((unsigned)h3 << 16);
    unsigned short l0 = bf2u(__float2bfloat16(x[0] - f0));
    unsigned short l1 = bf2u(__float2bfloat16(x[1] - f1));
    unsigned short l2 = bf2u(__float2bfloat16(x[2] - f2));
    unsigned short l3 = bf2u(__float2bfloat16(x[3] - f3));
    H[0] = (unsigned)h0 | ((unsigned)h1 << 16);
    H[1] = (unsigned)h2 | ((unsigned)h3 << 16);
    L[0] = (unsigned)l0 | ((unsigned)l1 << 16);
    L[1] = (unsigned)l2 | ((unsigned)l3 << 16);
}

__device__ __forceinline__ bf16x8 ldb128(const unsigned short* base, int byteoff) {
    return *(const bf16x8*)((const char*)base + byteoff);
}
__device__ __forceinline__ void stb64(unsigned short* base, int byteoff, u32x2 v) {
    *(u32x2*)((char*)base + byteoff) = v;
}

__global__ __launch_bounds__(NT, 2)
void ode_mfma12(const float* __restrict__ z0, const float* __restrict__ t,
                const float* __restrict__ W1, const float* __restrict__ b1,
                const float* __restrict__ W2, const float* __restrict__ b2,
                float* __restrict__ out)
{
    // z: bf16 H/L tiles (R6). a: int8 hi/lo tiles (scale 2^-15), [row][h] bytes.
    __shared__ __align__(16) unsigned short zHs[ROWS * Dsz], zLs[ROWS * Dsz];
    __shared__ __align__(16) signed char aH8[ROWS * Hsz], aL8[ROWS * Hsz];
    __shared__ float ts[Tsz];

    const int tid  = threadIdx.x;
    const int lane = tid & 63;
    const int w    = tid >> 6;   // wave: layer1 h-cols 32w..+31, layer2 d-cols 16w..+15
    const int g    = lane >> 4;
    const int c    = lane & 15;  // batch row within tile
    const int r0   = blockIdx.x * ROWS;

    if (tid < Tsz) ts[tid] = t[tid];

    // ---- z master in registers: zreg[reg] = z[batch=c][d = 16w + 4g + reg] ----
    f32x4 zreg = *(const f32x4*)&z0[(r0 + c) * Dsz + 16*w + 4*g];

    // ---- W1^T A-fragments (bf16 H/L, unchanged): W1T[h=16(2w+nt)+c][d=32kt+8g+i] ----
    bf16x8 w1tH[2][2], w1tL[2][2];   // [nt][kt]
    #pragma unroll
    for (int nt = 0; nt < 2; ++nt) {
        const int n = 32*w + 16*nt + c;
        #pragma unroll
        for (int kt = 0; kt < 2; ++kt) {
            float tmp[8];
            #pragma unroll
            for (int i = 0; i < 8; ++i) tmp[i] = W1[(32*kt + 8*g + i) * Hsz + n];
            split8(tmp, w1tH[nt][kt], w1tL[nt][kt]);
        }
    }
    // ---- W2^T int8 A-fragments, 3 byte-levels of w24 = rint(W2 * 2^25) ----
    // lane (g,c): A[m=c][k=16g+i] = W2T[d=16w+c][h=64*kt2+16g+i], i=0..15
    i32x4 w2hh[2], w2hl[2], w2ll[2];   // [kt2]
    {
        const int n = 16*w + c;
        #pragma unroll
        for (int kt2 = 0; kt2 < 2; ++kt2) {
            union { i32x4 v; signed char b[16]; } Ph, Pm, Pl;
            #pragma unroll
            for (int i = 0; i < 16; ++i) {
                float wv = W2[(64*kt2 + 16*g + i) * Dsz + n];
                int w24 = (int)rintf(wv * 33554432.f);          // 2^25
                w24 = w24 > 8355711 ? 8355711 : (w24 < -8421504 ? -8421504 : w24);
                int l0 = ((w24 + 128) & 255) - 128;
                int r1 = (w24 - l0) >> 8;
                int l1 = ((r1 + 128) & 255) - 128;
                int r2 = (r1 - l1) >> 8;
                Ph.b[i] = (signed char)r2;
                Pm.b[i] = (signed char)l1;
                Pl.b[i] = (signed char)l0;
            }
            w2hh[kt2] = Ph.v; w2hl[kt2] = Pm.v; w2ll[kt2] = Pl.v;
        }
    }
    f32x4 b1v[2], b2v;
    #pragma unroll
    for (int nt = 0; nt < 2; ++nt)
        #pragma unroll
        for (int reg = 0; reg < 4; ++reg)
            b1v[nt][reg] = b1[16*(2*w + nt) + 4*g + reg];
    #pragma unroll
    for (int reg = 0; reg < 4; ++reg) b2v[reg] = b2[16*w + 4*g + reg];

    // ---- loop-invariant swizzled LDS byte offsets ----
    const int zw = (c*128 + (16*w + 4*g)*2) ^ ((c & 7) << 4);          // b64 write
    int zrd[2], aw8[2], ar8[2];
    #pragma unroll
    for (int kt = 0; kt < 2; ++kt)
        zrd[kt] = (c*128 + (32*kt + 8*g)*2) ^ ((c & 7) << 4);          // b128 read
    #pragma unroll
    for (int nt = 0; nt < 2; ++nt)
        aw8[nt] = (c*128 + 32*w + 16*nt + 4*g) ^ ((c & 7) << 4);       // b32 write (4 int8)
    #pragma unroll
    for (int kt2 = 0; kt2 < 2; ++kt2)
        ar8[kt2] = (c*128 + 64*kt2 + 16*g) ^ ((c & 7) << 4);           // b128 read (16 int8)

    auto z_to_lds = [&]() {
        u32x2 H, L;
        splitq(zreg, H, L);
        stb64(zHs, zw, H);
        stb64(zLs, zw, L);
    };

    z_to_lds();
    __syncthreads();

    const int n_steps = (int)ceilf(fabsf(ts[1] - ts[0]) / 0.05f);   // = 2 (exact in f32)

    for (int iv = 0; iv < Tsz - 1; ++iv) {
        const float h = (ts[iv + 1] - ts[iv]) / (float)n_steps;
        for (int s = 0; s < n_steps; ++s) {
            // ---- layer 1 (transposed, bf16 3-product — unchanged from R6) ----
            bf16x8 zh0 = ldb128(zHs, zrd[0]), zh1 = ldb128(zHs, zrd[1]);
            bf16x8 zl0 = ldb128(zLs, zrd[0]), zl1 = ldb128(zLs, zrd[1]);
            #pragma unroll
            for (int nt = 0; nt < 2; ++nt) {
                f32x4 aA = b1v[nt];
                f32x4 aB = {0,0,0,0}, aC = {0,0,0,0};
                aA = MFMA(w1tH[nt][0], zh0, aA);
                aB = MFMA(w1tH[nt][0], zl0, aB);
                aC = MFMA(w1tL[nt][0], zh0, aC);
                aA = MFMA(w1tH[nt][1], zh1, aA);
                aB = MFMA(w1tH[nt][1], zl1, aB);
                aC = MFMA(w1tL[nt][1], zh1, aC);
                f32x4 av = (aA + aB) + aC;
                // tanh -> int16 (scale 2^15) -> balanced int8 split -> packed b32 stores
                int q[4];
                #pragma unroll
                for (int reg = 0; reg < 4; ++reg) {
                    float tv = fast_tanh(av[reg]);
                    int v = (int)rintf(tv * 32768.f);
                    q[reg] = v > 32639 ? 32639 : v;      // lower bound -32768 is representable
                }
                unsigned u0 = (unsigned)(q[0] + 128) & 255u;
                unsigned u1 = (unsigned)(q[1] + 128) & 255u;
                unsigned u2 = (unsigned)(q[2] + 128) & 255u;
                unsigned u3 = (unsigned)(q[3] + 128) & 255u;
                int h0 = (q[0] - ((int)u0 - 128)) >> 8;
                int h1 = (q[1] - ((int)u1 - 128)) >> 8;
                int h2 = (q[2] - ((int)u2 - 128)) >> 8;
                int h3 = (q[3] - ((int)u3 - 128)) >> 8;
                unsigned packL = (u0 | (u1 << 8) | (u2 << 16) | (u3 << 24)) ^ 0x80808080u;
                unsigned packH = (unsigned)(h0 & 255) | ((unsigned)(h1 & 255) << 8)
                               | ((unsigned)(h2 & 255) << 16) | ((unsigned)(h3 & 255) << 24);
                *(unsigned*)((char*)aH8 + aw8[nt]) = packH;
                *(unsigned*)((char*)aL8 + aw8[nt]) = packL;
            }
            __syncthreads();
            // ---- layer 2 (transposed, int8 K=64, exact integer 5-product) ----
            i32x4 ah0 = *(const i32x4*)((const char*)aH8 + ar8[0]);
            i32x4 ah1 = *(const i32x4*)((const char*)aH8 + ar8[1]);
            i32x4 al0 = *(const i32x4*)((const char*)aL8 + ar8[0]);
            i32x4 al1 = *(const i32x4*)((const char*)aL8 + ar8[1]);
            i32x4 q1 = {0,0,0,0}, q2 = {0,0,0,0}, q3 = {0,0,0,0};
            q1 = MFMAI(w2hh[0], ah0, q1);
            q2 = MFMAI(w2hh[0], al0, q2);
            q3 = MFMAI(w2hl[0], al0, q3);
            q1 = MFMAI(w2hh[1], ah1, q1);
            q2 = MFMAI(w2hh[1], al1, q2);
            q3 = MFMAI(w2hl[1], al1, q3);
            q2 = MFMAI(w2hl[0], ah0, q2);
            q3 = MFMAI(w2ll[0], ah0, q3);
            q2 = MFMAI(w2hl[1], ah1, q2);
            q3 = MFMAI(w2ll[1], ah1, q3);
            // dz = q1*2^-16 + q2*2^-24 + q3*2^-32 + b2 ; z += h*dz
            f32x4 dz;
            #pragma unroll
            for (int reg = 0; reg < 4; ++reg)
                dz[reg] = __builtin_fmaf((float)q1[reg], 0x1p-16f,
                          __builtin_fmaf((float)q2[reg], 0x1p-24f,
                          __builtin_fmaf((float)q3[reg], 0x1p-32f, b2v[reg])));
            zreg += h * dz;
            z_to_lds();                  // 2 b64 writes
            __syncthreads();
        }
    }

    // ---- write result (one dwordx4 per lane) ----
    *(f32x4*)&out[(r0 + c) * Dsz + 16*w + 4*g] = zreg;
}

extern "C" void kernel_launch(void* const* d_in, const int* in_sizes, int n_in,
                              void* d_out, int out_size, void* d_ws, size_t ws_size,
                              hipStream_t stream) {
    const float* z0 = (const float*)d_in[0];
    const float* t  = (const float*)d_in[1];
    const float* W1 = (const float*)d_in[2];
    const float* b1 = (const float*)d_in[3];
    const float* W2 = (const float*)d_in[4];
    const float* b2 = (const float*)d_in[5];
    float* out = (float*)d_out;
    (void)in_sizes; (void)n_in; (void)out_size; (void)d_ws; (void)ws_size;

    ode_mfma12<<<dim3(Bsz / ROWS), dim3(NT), 0, stream>>>(z0, t, W1, b1, W2, b2, out);
}

// Round 13
// 94.128 us; speedup vs baseline: 1.0993x; 1.0993x over previous
//
#include <hip/hip_runtime.h>
#include <hip/hip_bf16.h>

typedef float    f32x4  __attribute__((ext_vector_type(4)));
typedef short    bf16x8 __attribute__((ext_vector_type(8)));
typedef unsigned u32x2  __attribute__((ext_vector_type(2)));

#define Bsz  8192
#define Dsz  64
#define Hsz  128
#define Tsz  41
#define ROWS 16
#define NT   256

#define MFMA(a,b,c) __builtin_amdgcn_mfma_f32_16x16x32_bf16((a),(b),(c),0,0,0)

__device__ __forceinline__ float fast_tanh(float x) {
    float ax = __builtin_fabsf(x);
    float e  = __expf(-2.0f * ax);
    float r  = (1.0f - e) * __builtin_amdgcn_rcpf(1.0f + e);
    return __builtin_copysignf(r, x);
}

__device__ __forceinline__ unsigned short bf2u(__hip_bfloat16 h) {
    union { __hip_bfloat16 b; unsigned short u; } v; v.b = h; return v.u;
}

union FragU { bf16x8 f; unsigned short h[8]; };

// split 8 f32 into hi/lo bf16 fragments (weights, init only)
__device__ __forceinline__ void split8(const float* x, bf16x8& hi, bf16x8& lo) {
    FragU H, L;
    #pragma unroll
    for (int i = 0; i < 8; ++i) {
        __hip_bfloat16 hb = __float2bfloat16(x[i]);
        H.h[i] = bf2u(hb);
        L.h[i] = bf2u(__float2bfloat16(x[i] - __bfloat162float(hb)));
    }
    hi = H.f; lo = L.f;
}

// split f32x4 -> packed H (2 dwords) and packed L (compiler lowers casts to cvt_pk)
__device__ __forceinline__ void splitq(const f32x4& x, u32x2& H, u32x2& L) {
    unsigned short h0 = bf2u(__float2bfloat16(x[0]));
    unsigned short h1 = bf2u(__float2bfloat16(x[1]));
    unsigned short h2 = bf2u(__float2bfloat16(x[2]));
    unsigned short h3 = bf2u(__float2bfloat16(x[3]));
    float f0 = __uint_as_float((unsigned)h0 << 16);
    float f1 = __uint_as_float((unsigned)h1 << 16);
    float f2 = __uint_as_float((unsigned)h2 << 16);
    float f3 = __uint_as_float((unsigned)h3 << 16);
    unsigned short l0 = bf2u(__float2bfloat16(x[0] - f0));
    unsigned short l1 = bf2u(__float2bfloat16(x[1] - f1));
    unsigned short l2 = bf2u(__float2bfloat16(x[2] - f2));
    unsigned short l3 = bf2u(__float2bfloat16(x[3] - f3));
    H[0] = (unsigned)h0 | ((unsigned)h1 << 16);
    H[1] = (unsigned)h2 | ((unsigned)h3 << 16);
    L[0] = (unsigned)l0 | ((unsigned)l1 << 16);
    L[1] = (unsigned)l2 | ((unsigned)l3 << 16);
}

__device__ __forceinline__ bf16x8 ldb128(const unsigned short* base, int byteoff) {
    return *(const bf16x8*)((const char*)base + byteoff);
}
__device__ __forceinline__ void stb64(unsigned short* base, int byteoff, u32x2 v) {
    *(u32x2*)((char*)base + byteoff) = v;
}

__global__ __launch_bounds__(NT, 2)
void ode_mfma13(const float* __restrict__ z0, const float* __restrict__ t,
                const float* __restrict__ W1, const float* __restrict__ b1,
                const float* __restrict__ W2, const float* __restrict__ b2,
                float* __restrict__ out)
{
    // bf16 H/L tiles, [batch_row][feature], byte-index XOR-swizzled by (row&7)<<4
    __shared__ __align__(16) unsigned short zHs[ROWS * Dsz], zLs[ROWS * Dsz];
    __shared__ __align__(16) unsigned short aHs[ROWS * Hsz], aLs[ROWS * Hsz];
    __shared__ float ts[Tsz];

    const int tid  = threadIdx.x;
    const int lane = tid & 63;
    const int w    = tid >> 6;   // wave: layer1 h-cols 32w..+31, layer2 d-cols 16w..+15
    const int g    = lane >> 4;
    const int c    = lane & 15;  // batch row within tile
    const int r0   = blockIdx.x * ROWS;

    if (tid < Tsz) ts[tid] = t[tid];

    // ---- z master in registers: zreg[reg] = z[batch=c][d = 16w + 4g + reg] ----
    f32x4 zreg = *(const f32x4*)&z0[(r0 + c) * Dsz + 16*w + 4*g];

    // ---- W1^T A-fragments: lane holds W1T[h=16(2w+nt)+c][d=32kt+8g+i] ----
    bf16x8 w1tH[2][2], w1tL[2][2];   // [nt][kt]
    #pragma unroll
    for (int nt = 0; nt < 2; ++nt) {
        const int n = 32*w + 16*nt + c;
        #pragma unroll
        for (int kt = 0; kt < 2; ++kt) {
            float tmp[8];
            #pragma unroll
            for (int i = 0; i < 8; ++i) tmp[i] = W1[(32*kt + 8*g + i) * Hsz + n];
            split8(tmp, w1tH[nt][kt], w1tL[nt][kt]);
        }
    }
    // ---- W2^T A-fragments: lane holds W2T[d=16w+c][h=32kt2+8g+i] ----
    bf16x8 w2tH[4], w2tL[4];         // [kt2]
    {
        const int n = 16*w + c;
        #pragma unroll
        for (int kt2 = 0; kt2 < 4; ++kt2) {
            float tmp[8];
            #pragma unroll
            for (int i = 0; i < 8; ++i) tmp[i] = W2[(32*kt2 + 8*g + i) * Dsz + n];
            split8(tmp, w2tH[kt2], w2tL[kt2]);
        }
    }
    f32x4 b1v[2], b2v;
    #pragma unroll
    for (int nt = 0; nt < 2; ++nt)
        #pragma unroll
        for (int reg = 0; reg < 4; ++reg)
            b1v[nt][reg] = b1[16*(2*w + nt) + 4*g + reg];
    #pragma unroll
    for (int reg = 0; reg < 4; ++reg) b2v[reg] = b2[16*w + 4*g + reg];

    // ---- loop-invariant swizzled LDS byte offsets ----
    const int zw = (c*128 + (16*w + 4*g)*2) ^ ((c & 7) << 4);          // b64 write
    int zrd[2], aw[2], ard[4];
    #pragma unroll
    for (int kt = 0; kt < 2; ++kt)
        zrd[kt] = (c*128 + (32*kt + 8*g)*2) ^ ((c & 7) << 4);          // b128 read
    #pragma unroll
    for (int nt = 0; nt < 2; ++nt)
        aw[nt] = (c*256 + (32*w + 16*nt + 4*g)*2) ^ ((c & 7) << 4);    // b64 write
    #pragma unroll
    for (int kt2 = 0; kt2 < 4; ++kt2)
        ard[kt2] = (c*256 + (32*kt2 + 8*g)*2) ^ ((c & 7) << 4);        // b128 read

    auto z_to_lds = [&]() {
        u32x2 H, L;
        splitq(zreg, H, L);
        stb64(zHs, zw, H);
        stb64(zLs, zw, L);
    };

    z_to_lds();
    __syncthreads();

    // ---- anti-phase kick: the CU's second co-resident block (pairing: x and
    // x+256 share a CU for grid=512) starts one half-substep (~1536 cyc) late,
    // so its DS-burst phases overlap the partner's VALU/MFMA phases.
    if (blockIdx.x & 256) __builtin_amdgcn_s_sleep(24);

    const int n_steps = (int)ceilf(fabsf(ts[1] - ts[0]) / 0.05f);   // = 2 (exact in f32)

    for (int iv = 0; iv < Tsz - 1; ++iv) {
        const float h = (ts[iv + 1] - ts[iv]) / (float)n_steps;
        for (int s = 0; s < n_steps; ++s) {
            // ---- layer 1 (transposed): a^T = tanh(W1^T @ z^T + b1) ----
            bf16x8 zh0 = ldb128(zHs, zrd[0]), zh1 = ldb128(zHs, zrd[1]);
            bf16x8 zl0 = ldb128(zLs, zrd[0]), zl1 = ldb128(zLs, zrd[1]);
            #pragma unroll
            for (int nt = 0; nt < 2; ++nt) {
                f32x4 aA = b1v[nt];
                f32x4 aB = {0,0,0,0}, aC = {0,0,0,0};
                aA = MFMA(w1tH[nt][0], zh0, aA);
                aB = MFMA(w1tH[nt][0], zl0, aB);
                aC = MFMA(w1tL[nt][0], zh0, aC);
                aA = MFMA(w1tH[nt][1], zh1, aA);
                aB = MFMA(w1tH[nt][1], zl1, aB);
                aC = MFMA(w1tL[nt][1], zh1, aC);
                f32x4 av = (aA + aB) + aC;
                f32x4 tv;
                #pragma unroll
                for (int reg = 0; reg < 4; ++reg) tv[reg] = fast_tanh(av[reg]);
                u32x2 H, L;
                splitq(tv, H, L);
                stb64(aHs, aw[nt], H);
                stb64(aLs, aw[nt], L);
            }
            __syncthreads();
            // ---- layer 2 (transposed): dz^T = W2^T @ a^T + b2 ----
            bf16x8 ah0 = ldb128(aHs, ard[0]), ah1 = ldb128(aHs, ard[1]);
            bf16x8 ah2 = ldb128(aHs, ard[2]), ah3 = ldb128(aHs, ard[3]);
            bf16x8 al0 = ldb128(aLs, ard[0]), al1 = ldb128(aLs, ard[1]);
            bf16x8 al2 = ldb128(aLs, ard[2]), al3 = ldb128(aLs, ard[3]);
            f32x4 dA = b2v;
            f32x4 dB = {0,0,0,0}, dC = {0,0,0,0};
            dA = MFMA(w2tH[0], ah0, dA);
            dB = MFMA(w2tH[0], al0, dB);
            dC = MFMA(w2tL[0], ah0, dC);
            dA = MFMA(w2tH[1], ah1, dA);
            dB = MFMA(w2tH[1], al1, dB);
            dC = MFMA(w2tL[1], ah1, dC);
            dA = MFMA(w2tH[2], ah2, dA);
            dB = MFMA(w2tH[2], al2, dB);
            dC = MFMA(w2tL[2], ah2, dC);
            dA = MFMA(w2tH[3], ah3, dA);
            dB = MFMA(w2tH[3], al3, dB);
            dC = MFMA(w2tL[3], ah3, dC);
            f32x4 dz = (dA + dB) + dC;
            zreg += h * dz;
            z_to_lds();                  // 2 b64 writes
            __syncthreads();
        }
    }

    // ---- write result (one dwordx4 per lane) ----
    *(f32x4*)&out[(r0 + c) * Dsz + 16*w + 4*g] = zreg;
}

extern "C" void kernel_launch(void* const* d_in, const int* in_sizes, int n_in,
                              void* d_out, int out_size, void* d_ws, size_t ws_size,
                              hipStream_t stream) {
    const float* z0 = (const float*)d_in[0];
    const float* t  = (const float*)d_in[1];
    const float* W1 = (const float*)d_in[2];
    const float* b1 = (const float*)d_in[3];
    const float* W2 = (const float*)d_in[4];
    const float* b2 = (const float*)d_in[5];
    float* out = (float*)d_out;
    (void)in_sizes; (void)n_in; (void)out_size; (void)d_ws; (void)ws_size;

    ode_mfma13<<<dim3(Bsz / ROWS), dim3(NT), 0, stream>>>(z0, t, W1, b1, W2, b2, out);
}

// Round 14
// 88.316 us; speedup vs baseline: 1.1717x; 1.0658x over previous
//
#include <hip/hip_runtime.h>
#include <hip/hip_bf16.h>

typedef float          f32x4  __attribute__((ext_vector_type(4)));
typedef short          bf16x8 __attribute__((ext_vector_type(8)));
typedef unsigned short u16x4  __attribute__((ext_vector_type(4)));

#define Bsz  8192
#define Dsz  64
#define Hsz  128
#define Tsz  41
#define ROWS 16
#define NT   256

#define MFMA(a,b,c) __builtin_amdgcn_mfma_f32_16x16x32_bf16((a),(b),(c),0,0,0)

__device__ __forceinline__ float fast_tanh(float x) {
    float ax = __builtin_fabsf(x);
    float e  = __expf(-2.0f * ax);
    float r  = (1.0f - e) * __builtin_amdgcn_rcpf(1.0f + e);
    return __builtin_copysignf(r, x);
}

__device__ __forceinline__ unsigned short bf2u(__hip_bfloat16 h) {
    union { __hip_bfloat16 b; unsigned short u; } v; v.b = h; return v.u;
}

union FragU { bf16x8 f; unsigned short h[8]; };

// split 8 f32 into hi/lo bf16 fragments (weights, init only)
__device__ __forceinline__ void split8(const float* x, bf16x8& hi, bf16x8& lo) {
    FragU H, L;
    #pragma unroll
    for (int i = 0; i < 8; ++i) {
        __hip_bfloat16 hb = __float2bfloat16(x[i]);
        H.h[i] = bf2u(hb);
        L.h[i] = bf2u(__float2bfloat16(x[i] - __bfloat162float(hb)));
    }
    hi = H.f; lo = L.f;
}

// split an f32x4 into H/L bf16 quads (for one b64 store each)
__device__ __forceinline__ void splitq(const f32x4& x, u16x4& H, u16x4& L) {
    #pragma unroll
    for (int i = 0; i < 4; ++i) {
        __hip_bfloat16 hb = __float2bfloat16(x[i]);
        H[i] = bf2u(hb);
        L[i] = bf2u(__float2bfloat16(x[i] - __bfloat162float(hb)));
    }
}

__device__ __forceinline__ bf16x8 ldb128(const unsigned short* base, int byteoff) {
    return *(const bf16x8*)((const char*)base + byteoff);
}
__device__ __forceinline__ void stb64(unsigned short* base, int byteoff, u16x4 v) {
    *(u16x4*)((char*)base + byteoff) = v;
}

__global__ __launch_bounds__(NT, 2)
void ode_mfma6(const float* __restrict__ z0, const float* __restrict__ t,
               const float* __restrict__ W1, const float* __restrict__ b1,
               const float* __restrict__ W2, const float* __restrict__ b2,
               float* __restrict__ out)
{
    // bf16 H/L tiles, [batch_row][feature], byte-index XOR-swizzled by (row&7)<<4
    __shared__ __align__(16) unsigned short zHs[ROWS * Dsz], zLs[ROWS * Dsz];
    __shared__ __align__(16) unsigned short aHs[ROWS * Hsz], aLs[ROWS * Hsz];
    __shared__ float ts[Tsz];

    const int tid  = threadIdx.x;
    const int lane = tid & 63;
    const int w    = tid >> 6;   // wave: layer1 h-cols 32w..+31, layer2 d-cols 16w..+15
    const int g    = lane >> 4;
    const int c    = lane & 15;  // batch row within tile
    const int r0   = blockIdx.x * ROWS;

    if (tid < Tsz) ts[tid] = t[tid];

    // ---- z master in registers (transposed layer2 D layout):
    //      zreg[reg] = z[batch=c][d = 16w + 4g + reg]  -> one dwordx4 ----
    f32x4 zreg = *(const f32x4*)&z0[(r0 + c) * Dsz + 16*w + 4*g];

    // ---- W1^T A-fragments: lane holds W1T[h=16(2w+nt)+c][d=32kt+8g+i] ----
    bf16x8 w1tH[2][2], w1tL[2][2];   // [nt][kt]
    #pragma unroll
    for (int nt = 0; nt < 2; ++nt) {
        const int n = 32*w + 16*nt + c;
        #pragma unroll
        for (int kt = 0; kt < 2; ++kt) {
            float tmp[8];
            #pragma unroll
            for (int i = 0; i < 8; ++i) tmp[i] = W1[(32*kt + 8*g + i) * Hsz + n];
            split8(tmp, w1tH[nt][kt], w1tL[nt][kt]);
        }
    }
    // ---- W2^T A-fragments: lane holds W2T[d=16w+c][h=32kt2+8g+i] ----
    bf16x8 w2tH[4], w2tL[4];         // [kt2]
    {
        const int n = 16*w + c;
        #pragma unroll
        for (int kt2 = 0; kt2 < 4; ++kt2) {
            float tmp[8];
            #pragma unroll
            for (int i = 0; i < 8; ++i) tmp[i] = W2[(32*kt2 + 8*g + i) * Dsz + n];
            split8(tmp, w2tH[kt2], w2tL[kt2]);
        }
    }
    // biases along the transposed D rows (4 consecutive features per lane)
    f32x4 b1v[2], b2v;
    #pragma unroll
    for (int nt = 0; nt < 2; ++nt)
        #pragma unroll
        for (int reg = 0; reg < 4; ++reg)
            b1v[nt][reg] = b1[16*(2*w + nt) + 4*g + reg];
    #pragma unroll
    for (int reg = 0; reg < 4; ++reg) b2v[reg] = b2[16*w + 4*g + reg];

    // ---- loop-invariant swizzled LDS byte offsets ----
    const int zw = (c*128 + (16*w + 4*g)*2) ^ ((c & 7) << 4);          // b64 write
    int zrd[2], aw[2], ard[4];
    #pragma unroll
    for (int kt = 0; kt < 2; ++kt)
        zrd[kt] = (c*128 + (32*kt + 8*g)*2) ^ ((c & 7) << 4);          // b128 read
    #pragma unroll
    for (int nt = 0; nt < 2; ++nt)
        aw[nt] = (c*256 + (32*w + 16*nt + 4*g)*2) ^ ((c & 7) << 4);    // b64 write
    #pragma unroll
    for (int kt2 = 0; kt2 < 4; ++kt2)
        ard[kt2] = (c*256 + (32*kt2 + 8*g)*2) ^ ((c & 7) << 4);        // b128 read

    auto z_to_lds = [&]() {
        u16x4 H, L;
        splitq(zreg, H, L);
        stb64(zHs, zw, H);
        stb64(zLs, zw, L);
    };

    z_to_lds();
    __syncthreads();

    const int n_steps = (int)ceilf(fabsf(ts[1] - ts[0]) / 0.05f);   // = 2 (exact in f32)

    for (int iv = 0; iv < Tsz - 1; ++iv) {
        const float h = (ts[iv + 1] - ts[iv]) / (float)n_steps;
        for (int s = 0; s < n_steps; ++s) {
            // ---- layer 1 (transposed): a^T = tanh(W1^T @ z^T + b1) ----
            bf16x8 zh0 = ldb128(zHs, zrd[0]), zh1 = ldb128(zHs, zrd[1]);
            bf16x8 zl0 = ldb128(zLs, zrd[0]), zl1 = ldb128(zLs, zrd[1]);
            #pragma unroll
            for (int nt = 0; nt < 2; ++nt) {
                f32x4 aA = b1v[nt];
                f32x4 aB = {0,0,0,0}, aC = {0,0,0,0};
                aA = MFMA(w1tH[nt][0], zh0, aA);
                aB = MFMA(w1tH[nt][0], zl0, aB);
                aC = MFMA(w1tL[nt][0], zh0, aC);
                aA = MFMA(w1tH[nt][1], zh1, aA);
                aB = MFMA(w1tH[nt][1], zl1, aB);
                aC = MFMA(w1tL[nt][1], zh1, aC);
                f32x4 av = (aA + aB) + aC;
                f32x4 tv;
                #pragma unroll
                for (int reg = 0; reg < 4; ++reg) tv[reg] = fast_tanh(av[reg]);
                u16x4 H, L;
                splitq(tv, H, L);
                stb64(aHs, aw[nt], H);    // lane holds 4 consecutive h -> one b64
                stb64(aLs, aw[nt], L);
            }
            __syncthreads();
            // ---- layer 2 (transposed): dz^T = W2^T @ a^T + b2 ----
            bf16x8 ah0 = ldb128(aHs, ard[0]), ah1 = ldb128(aHs, ard[1]);
            bf16x8 ah2 = ldb128(aHs, ard[2]), ah3 = ldb128(aHs, ard[3]);
            bf16x8 al0 = ldb128(aLs, ard[0]), al1 = ldb128(aLs, ard[1]);
            bf16x8 al2 = ldb128(aLs, ard[2]), al3 = ldb128(aLs, ard[3]);
            f32x4 dA = b2v;
            f32x4 dB = {0,0,0,0}, dC = {0,0,0,0};
            dA = MFMA(w2tH[0], ah0, dA);
            dB = MFMA(w2tH[0], al0, dB);
            dC = MFMA(w2tL[0], ah0, dC);
            dA = MFMA(w2tH[1], ah1, dA);
            dB = MFMA(w2tH[1], al1, dB);
            dC = MFMA(w2tL[1], ah1, dC);
            dA = MFMA(w2tH[2], ah2, dA);
            dB = MFMA(w2tH[2], al2, dB);
            dC = MFMA(w2tL[2], ah2, dC);
            dA = MFMA(w2tH[3], ah3, dA);
            dB = MFMA(w2tH[3], al3, dB);
            dC = MFMA(w2tL[3], ah3, dC);
            f32x4 dz = (dA + dB) + dC;
            zreg += h * dz;
            z_to_lds();                  // 2 b64 writes
            __syncthreads();
        }
    }

    // ---- write result (one dwordx4 per lane) ----
    *(f32x4*)&out[(r0 + c) * Dsz + 16*w + 4*g] = zreg;
}

extern "C" void kernel_launch(void* const* d_in, const int* in_sizes, int n_in,
                              void* d_out, int out_size, void* d_ws, size_t ws_size,
                              hipStream_t stream) {
    const float* z0 = (const float*)d_in[0];
    const float* t  = (const float*)d_in[1];
    const float* W1 = (const float*)d_in[2];
    const float* b1 = (const float*)d_in[3];
    const float* W2 = (const float*)d_in[4];
    const float* b2 = (const float*)d_in[5];
    float* out = (float*)d_out;
    (void)in_sizes; (void)n_in; (void)out_size; (void)d_ws; (void)ws_size;

    ode_mfma6<<<dim3(Bsz / ROWS), dim3(NT), 0, stream>>>(z0, t, W1, b1, W2, b2, out);
}

// Round 15
// 76.205 us; speedup vs baseline: 1.3579x; 1.1589x over previous
//
#include <hip/hip_runtime.h>
#include <hip/hip_bf16.h>

typedef float          f32x4  __attribute__((ext_vector_type(4)));
typedef short          bf16x8 __attribute__((ext_vector_type(8)));
typedef unsigned short u16x4  __attribute__((ext_vector_type(4)));

#define Bsz  8192
#define Dsz  64
#define Hsz  128
#define Tsz  41
#define ROWS 16
#define NT   256

#define MFMA(a,b,c) __builtin_amdgcn_mfma_f32_16x16x32_bf16((a),(b),(c),0,0,0)

__device__ __forceinline__ float fast_tanh(float x) {
    float ax = __builtin_fabsf(x);
    float e  = __expf(-2.0f * ax);
    float r  = (1.0f - e) * __builtin_amdgcn_rcpf(1.0f + e);
    return __builtin_copysignf(r, x);
}

__device__ __forceinline__ unsigned short bf2u(__hip_bfloat16 h) {
    union { __hip_bfloat16 b; unsigned short u; } v; v.b = h; return v.u;
}

union FragU { bf16x8 f; unsigned short h[8]; };

// split 8 f32 into hi/lo bf16 fragments (weights, init only)
__device__ __forceinline__ void split8(const float* x, bf16x8& hi, bf16x8& lo) {
    FragU H, L;
    #pragma unroll
    for (int i = 0; i < 8; ++i) {
        __hip_bfloat16 hb = __float2bfloat16(x[i]);
        H.h[i] = bf2u(hb);
        L.h[i] = bf2u(__float2bfloat16(x[i] - __bfloat162float(hb)));
    }
    hi = H.f; lo = L.f;
}

// split an f32x4 into H/L bf16 quads (z path)
__device__ __forceinline__ void splitq(const f32x4& x, u16x4& H, u16x4& L) {
    #pragma unroll
    for (int i = 0; i < 4; ++i) {
        __hip_bfloat16 hb = __float2bfloat16(x[i]);
        H[i] = bf2u(hb);
        L[i] = bf2u(__float2bfloat16(x[i] - __bfloat162float(hb)));
    }
}

// plain bf16 quad pack (a path — residual dropped by design)
__device__ __forceinline__ u16x4 packq(const f32x4& x) {
    u16x4 H;
    #pragma unroll
    for (int i = 0; i < 4; ++i) H[i] = bf2u(__float2bfloat16(x[i]));
    return H;
}

__device__ __forceinline__ bf16x8 ldb128(const unsigned short* base, int byteoff) {
    return *(const bf16x8*)((const char*)base + byteoff);
}
__device__ __forceinline__ void stb64(unsigned short* base, int byteoff, u16x4 v) {
    *(u16x4*)((char*)base + byteoff) = v;
}

__global__ __launch_bounds__(NT, 2)
void ode_mfma15(const float* __restrict__ z0, const float* __restrict__ t,
                const float* __restrict__ W1, const float* __restrict__ b1,
                const float* __restrict__ W2, const float* __restrict__ b2,
                float* __restrict__ out)
{
    // z: bf16 H/L tiles; a: single bf16 tile (residual dropped — weights carry
    // their own residual in registers). [batch_row][feature], XOR-swizzled bytes.
    __shared__ __align__(16) unsigned short zHs[ROWS * Dsz], zLs[ROWS * Dsz];
    __shared__ __align__(16) unsigned short aHs[ROWS * Hsz];
    __shared__ float ts[Tsz];

    const int tid  = threadIdx.x;
    const int lane = tid & 63;
    const int w    = tid >> 6;   // wave: layer1 h-cols 32w..+31, layer2 d-cols 16w..+15
    const int g    = lane >> 4;
    const int c    = lane & 15;  // batch row within tile
    const int r0   = blockIdx.x * ROWS;

    if (tid < Tsz) ts[tid] = t[tid];

    // ---- z master in registers: zreg[reg] = z[batch=c][d = 16w + 4g + reg] ----
    f32x4 zreg = *(const f32x4*)&z0[(r0 + c) * Dsz + 16*w + 4*g];

    // ---- W1^T A-fragments: lane holds W1T[h=16(2w+nt)+c][d=32kt+8g+i] ----
    bf16x8 w1tH[2][2], w1tL[2][2];   // [nt][kt]
    #pragma unroll
    for (int nt = 0; nt < 2; ++nt) {
        const int n = 32*w + 16*nt + c;
        #pragma unroll
        for (int kt = 0; kt < 2; ++kt) {
            float tmp[8];
            #pragma unroll
            for (int i = 0; i < 8; ++i) tmp[i] = W1[(32*kt + 8*g + i) * Hsz + n];
            split8(tmp, w1tH[nt][kt], w1tL[nt][kt]);
        }
    }
    // ---- W2^T A-fragments: lane holds W2T[d=16w+c][h=32kt2+8g+i] ----
    bf16x8 w2tH[4], w2tL[4];         // [kt2]
    {
        const int n = 16*w + c;
        #pragma unroll
        for (int kt2 = 0; kt2 < 4; ++kt2) {
            float tmp[8];
            #pragma unroll
            for (int i = 0; i < 8; ++i) tmp[i] = W2[(32*kt2 + 8*g + i) * Dsz + n];
            split8(tmp, w2tH[kt2], w2tL[kt2]);
        }
    }
    f32x4 b1v[2], b2v;
    #pragma unroll
    for (int nt = 0; nt < 2; ++nt)
        #pragma unroll
        for (int reg = 0; reg < 4; ++reg)
            b1v[nt][reg] = b1[16*(2*w + nt) + 4*g + reg];
    #pragma unroll
    for (int reg = 0; reg < 4; ++reg) b2v[reg] = b2[16*w + 4*g + reg];

    // ---- loop-invariant swizzled LDS byte offsets ----
    const int zw = (c*128 + (16*w + 4*g)*2) ^ ((c & 7) << 4);          // b64 write
    int zrd[2], aw[2], ard[4];
    #pragma unroll
    for (int kt = 0; kt < 2; ++kt)
        zrd[kt] = (c*128 + (32*kt + 8*g)*2) ^ ((c & 7) << 4);          // b128 read
    #pragma unroll
    for (int nt = 0; nt < 2; ++nt)
        aw[nt] = (c*256 + (32*w + 16*nt + 4*g)*2) ^ ((c & 7) << 4);    // b64 write
    #pragma unroll
    for (int kt2 = 0; kt2 < 4; ++kt2)
        ard[kt2] = (c*256 + (32*kt2 + 8*g)*2) ^ ((c & 7) << 4);        // b128 read

    auto z_to_lds = [&]() {
        u16x4 H, L;
        splitq(zreg, H, L);
        stb64(zHs, zw, H);
        stb64(zLs, zw, L);
    };

    z_to_lds();
    __syncthreads();

    const int n_steps = (int)ceilf(fabsf(ts[1] - ts[0]) / 0.05f);   // = 2 (exact in f32)

    for (int iv = 0; iv < Tsz - 1; ++iv) {
        const float h = (ts[iv + 1] - ts[iv]) / (float)n_steps;
        for (int s = 0; s < n_steps; ++s) {
            // ---- layer 1 (transposed): a^T = tanh(W1^T @ z^T + b1), 3-product ----
            bf16x8 zh0 = ldb128(zHs, zrd[0]), zh1 = ldb128(zHs, zrd[1]);
            bf16x8 zl0 = ldb128(zLs, zrd[0]), zl1 = ldb128(zLs, zrd[1]);
            #pragma unroll
            for (int nt = 0; nt < 2; ++nt) {
                f32x4 aA = b1v[nt];
                f32x4 aB = {0,0,0,0}, aC = {0,0,0,0};
                aA = MFMA(w1tH[nt][0], zh0, aA);
                aB = MFMA(w1tH[nt][0], zl0, aB);
                aC = MFMA(w1tL[nt][0], zh0, aC);
                aA = MFMA(w1tH[nt][1], zh1, aA);
                aB = MFMA(w1tH[nt][1], zl1, aB);
                aC = MFMA(w1tL[nt][1], zh1, aC);
                f32x4 av = (aA + aB) + aC;
                f32x4 tv;
                #pragma unroll
                for (int reg = 0; reg < 4; ++reg) tv[reg] = fast_tanh(av[reg]);
                stb64(aHs, aw[nt], packq(tv));   // plain bf16 a — one b64 store
            }
            __syncthreads();
            // ---- layer 2 (transposed): dz^T = (Hw2 + Lw2) @ bf16(a^T) + b2 ----
            bf16x8 ah0 = ldb128(aHs, ard[0]), ah1 = ldb128(aHs, ard[1]);
            bf16x8 ah2 = ldb128(aHs, ard[2]), ah3 = ldb128(aHs, ard[3]);
            f32x4 dA = b2v;
            f32x4 dB = {0,0,0,0}, dC = {0,0,0,0}, dD = {0,0,0,0};
            dA = MFMA(w2tH[0], ah0, dA);
            dB = MFMA(w2tH[1], ah1, dB);
            dC = MFMA(w2tL[0], ah0, dC);
            dD = MFMA(w2tL[1], ah1, dD);
            dA = MFMA(w2tH[2], ah2, dA);
            dB = MFMA(w2tH[3], ah3, dB);
            dC = MFMA(w2tL[2], ah2, dC);
            dD = MFMA(w2tL[3], ah3, dD);
            f32x4 dz = (dA + dB) + (dC + dD);
            zreg += h * dz;
            z_to_lds();                  // 2 b64 writes
            __syncthreads();
        }
    }

    // ---- write result (one dwordx4 per lane) ----
    *(f32x4*)&out[(r0 + c) * Dsz + 16*w + 4*g] = zreg;
}

extern "C" void kernel_launch(void* const* d_in, const int* in_sizes, int n_in,
                              void* d_out, int out_size, void* d_ws, size_t ws_size,
                              hipStream_t stream) {
    const float* z0 = (const float*)d_in[0];
    const float* t  = (const float*)d_in[1];
    const float* W1 = (const float*)d_in[2];
    const float* b1 = (const float*)d_in[3];
    const float* W2 = (const float*)d_in[4];
    const float* b2 = (const float*)d_in[5];
    float* out = (float*)d_out;
    (void)in_sizes; (void)n_in; (void)out_size; (void)d_ws; (void)ws_size;

    ode_mfma15<<<dim3(Bsz / ROWS), dim3(NT), 0, stream>>>(z0, t, W1, b1, W2, b2, out);
}

// Round 16
// 66.831 us; speedup vs baseline: 1.5483x; 1.1403x over previous
//
#include <hip/hip_runtime.h>
#include <hip/hip_bf16.h>

typedef float          f32x4  __attribute__((ext_vector_type(4)));
typedef short          bf16x8 __attribute__((ext_vector_type(8)));
typedef unsigned short u16x4  __attribute__((ext_vector_type(4)));

#define Bsz  8192
#define Dsz  64
#define Hsz  128
#define Tsz  41
#define ROWS 16
#define NT   256

#define MFMA(a,b,c) __builtin_amdgcn_mfma_f32_16x16x32_bf16((a),(b),(c),0,0,0)

__device__ __forceinline__ float fast_tanh(float x) {
    float ax = __builtin_fabsf(x);
    float e  = __expf(-2.0f * ax);
    float r  = (1.0f - e) * __builtin_amdgcn_rcpf(1.0f + e);
    return __builtin_copysignf(r, x);
}

__device__ __forceinline__ unsigned short bf2u(__hip_bfloat16 h) {
    union { __hip_bfloat16 b; unsigned short u; } v; v.b = h; return v.u;
}

union FragU { bf16x8 f; unsigned short h[8]; };

// split 8 f32 into hi/lo bf16 fragments (weights, init only — residuals live
// in registers and cost only MFMA issue, which is at 25% util)
__device__ __forceinline__ void split8(const float* x, bf16x8& hi, bf16x8& lo) {
    FragU H, L;
    #pragma unroll
    for (int i = 0; i < 8; ++i) {
        __hip_bfloat16 hb = __float2bfloat16(x[i]);
        H.h[i] = bf2u(hb);
        L.h[i] = bf2u(__float2bfloat16(x[i] - __bfloat162float(hb)));
    }
    hi = H.f; lo = L.f;
}

// plain bf16 quad pack (z and a operand paths — residuals dropped by design;
// R12/R15 showed output absmax is insensitive to operand precision at this level)
__device__ __forceinline__ u16x4 packq(const f32x4& x) {
    u16x4 H;
    #pragma unroll
    for (int i = 0; i < 4; ++i) H[i] = bf2u(__float2bfloat16(x[i]));
    return H;
}

__device__ __forceinline__ bf16x8 ldb128(const unsigned short* base, int byteoff) {
    return *(const bf16x8*)((const char*)base + byteoff);
}
__device__ __forceinline__ void stb64(unsigned short* base, int byteoff, u16x4 v) {
    *(u16x4*)((char*)base + byteoff) = v;
}

__global__ __launch_bounds__(NT, 2)
void ode_mfma16(const float* __restrict__ z0, const float* __restrict__ t,
                const float* __restrict__ W1, const float* __restrict__ b1,
                const float* __restrict__ W2, const float* __restrict__ b2,
                float* __restrict__ out)
{
    // z and a: single plain-bf16 tiles. Weight H/L residuals in registers.
    // [batch_row][feature], byte-index XOR-swizzled by (row&7)<<4.
    __shared__ __align__(16) unsigned short zHs[ROWS * Dsz];
    __shared__ __align__(16) unsigned short aHs[ROWS * Hsz];
    __shared__ float ts[Tsz];

    const int tid  = threadIdx.x;
    const int lane = tid & 63;
    const int w    = tid >> 6;   // wave: layer1 h-cols 32w..+31, layer2 d-cols 16w..+15
    const int g    = lane >> 4;
    const int c    = lane & 15;  // batch row within tile
    const int r0   = blockIdx.x * ROWS;

    if (tid < Tsz) ts[tid] = t[tid];

    // ---- z master in registers: zreg[reg] = z[batch=c][d = 16w + 4g + reg] ----
    f32x4 zreg = *(const f32x4*)&z0[(r0 + c) * Dsz + 16*w + 4*g];

    // ---- W1^T A-fragments: lane holds W1T[h=16(2w+nt)+c][d=32kt+8g+i] ----
    bf16x8 w1tH[2][2], w1tL[2][2];   // [nt][kt]
    #pragma unroll
    for (int nt = 0; nt < 2; ++nt) {
        const int n = 32*w + 16*nt + c;
        #pragma unroll
        for (int kt = 0; kt < 2; ++kt) {
            float tmp[8];
            #pragma unroll
            for (int i = 0; i < 8; ++i) tmp[i] = W1[(32*kt + 8*g + i) * Hsz + n];
            split8(tmp, w1tH[nt][kt], w1tL[nt][kt]);
        }
    }
    // ---- W2^T A-fragments: lane holds W2T[d=16w+c][h=32kt2+8g+i] ----
    bf16x8 w2tH[4], w2tL[4];         // [kt2]
    {
        const int n = 16*w + c;
        #pragma unroll
        for (int kt2 = 0; kt2 < 4; ++kt2) {
            float tmp[8];
            #pragma unroll
            for (int i = 0; i < 8; ++i) tmp[i] = W2[(32*kt2 + 8*g + i) * Dsz + n];
            split8(tmp, w2tH[kt2], w2tL[kt2]);
        }
    }
    f32x4 b1v[2], b2v;
    #pragma unroll
    for (int nt = 0; nt < 2; ++nt)
        #pragma unroll
        for (int reg = 0; reg < 4; ++reg)
            b1v[nt][reg] = b1[16*(2*w + nt) + 4*g + reg];
    #pragma unroll
    for (int reg = 0; reg < 4; ++reg) b2v[reg] = b2[16*w + 4*g + reg];

    // ---- loop-invariant swizzled LDS byte offsets ----
    const int zw = (c*128 + (16*w + 4*g)*2) ^ ((c & 7) << 4);          // b64 write
    int zrd[2], aw[2], ard[4];
    #pragma unroll
    for (int kt = 0; kt < 2; ++kt)
        zrd[kt] = (c*128 + (32*kt + 8*g)*2) ^ ((c & 7) << 4);          // b128 read
    #pragma unroll
    for (int nt = 0; nt < 2; ++nt)
        aw[nt] = (c*256 + (32*w + 16*nt + 4*g)*2) ^ ((c & 7) << 4);    // b64 write
    #pragma unroll
    for (int kt2 = 0; kt2 < 4; ++kt2)
        ard[kt2] = (c*256 + (32*kt2 + 8*g)*2) ^ ((c & 7) << 4);        // b128 read

    auto z_to_lds = [&]() {
        stb64(zHs, zw, packq(zreg));     // one b64 — residual dropped
    };

    z_to_lds();
    __syncthreads();

    const int n_steps = (int)ceilf(fabsf(ts[1] - ts[0]) / 0.05f);   // = 2 (exact in f32)

    for (int iv = 0; iv < Tsz - 1; ++iv) {
        const float h = (ts[iv + 1] - ts[iv]) / (float)n_steps;
        for (int s = 0; s < n_steps; ++s) {
            // ---- layer 1 (transposed): a^T = tanh((Hw1+Lw1) @ bf16(z^T) + b1) ----
            bf16x8 zh0 = ldb128(zHs, zrd[0]), zh1 = ldb128(zHs, zrd[1]);
            #pragma unroll
            for (int nt = 0; nt < 2; ++nt) {
                f32x4 aA = b1v[nt];
                f32x4 aB = {0,0,0,0};
                aA = MFMA(w1tH[nt][0], zh0, aA);
                aB = MFMA(w1tL[nt][0], zh0, aB);
                aA = MFMA(w1tH[nt][1], zh1, aA);
                aB = MFMA(w1tL[nt][1], zh1, aB);
                f32x4 av = aA + aB;
                f32x4 tv;
                #pragma unroll
                for (int reg = 0; reg < 4; ++reg) tv[reg] = fast_tanh(av[reg]);
                stb64(aHs, aw[nt], packq(tv));   // plain bf16 a — one b64 store
            }
            __syncthreads();
            // ---- layer 2 (transposed): dz^T = (Hw2 + Lw2) @ bf16(a^T) + b2 ----
            bf16x8 ah0 = ldb128(aHs, ard[0]), ah1 = ldb128(aHs, ard[1]);
            bf16x8 ah2 = ldb128(aHs, ard[2]), ah3 = ldb128(aHs, ard[3]);
            f32x4 dA = b2v;
            f32x4 dB = {0,0,0,0}, dC = {0,0,0,0}, dD = {0,0,0,0};
            dA = MFMA(w2tH[0], ah0, dA);
            dB = MFMA(w2tH[1], ah1, dB);
            dC = MFMA(w2tL[0], ah0, dC);
            dD = MFMA(w2tL[1], ah1, dD);
            dA = MFMA(w2tH[2], ah2, dA);
            dB = MFMA(w2tH[3], ah3, dB);
            dC = MFMA(w2tL[2], ah2, dC);
            dD = MFMA(w2tL[3], ah3, dD);
            f32x4 dz = (dA + dB) + (dC + dD);
            zreg += h * dz;
            z_to_lds();                  // 1 b64 write
            __syncthreads();
        }
    }

    // ---- write result (one dwordx4 per lane) ----
    *(f32x4*)&out[(r0 + c) * Dsz + 16*w + 4*g] = zreg;
}

extern "C" void kernel_launch(void* const* d_in, const int* in_sizes, int n_in,
                              void* d_out, int out_size, void* d_ws, size_t ws_size,
                              hipStream_t stream) {
    const float* z0 = (const float*)d_in[0];
    const float* t  = (const float*)d_in[1];
    const float* W1 = (const float*)d_in[2];
    const float* b1 = (const float*)d_in[3];
    const float* W2 = (const float*)d_in[4];
    const float* b2 = (const float*)d_in[5];
    float* out = (float*)d_out;
    (void)in_sizes; (void)n_in; (void)out_size; (void)d_ws; (void)ws_size;

    ode_mfma16<<<dim3(Bsz / ROWS), dim3(NT), 0, stream>>>(z0, t, W1, b1, W2, b2, out);
}

// Round 17
// 57.775 us; speedup vs baseline: 1.7910x; 1.1567x over previous
//
#include <hip/hip_runtime.h>
#include <hip/hip_bf16.h>

typedef float          f32x4  __attribute__((ext_vector_type(4)));
typedef short          bf16x8 __attribute__((ext_vector_type(8)));
typedef unsigned short u16x4  __attribute__((ext_vector_type(4)));

#define Bsz  8192
#define Dsz  64
#define Hsz  128
#define Tsz  41
#define ROWS 16
#define NT   256

#define MFMA(a,b,c) __builtin_amdgcn_mfma_f32_16x16x32_bf16((a),(b),(c),0,0,0)

__device__ __forceinline__ float fast_tanh(float x) {
    float ax = __builtin_fabsf(x);
    float e  = __expf(-2.0f * ax);
    float r  = (1.0f - e) * __builtin_amdgcn_rcpf(1.0f + e);
    return __builtin_copysignf(r, x);
}

__device__ __forceinline__ unsigned short bf2u(__hip_bfloat16 h) {
    union { __hip_bfloat16 b; unsigned short u; } v; v.b = h; return v.u;
}

union FragU { bf16x8 f; unsigned short h[8]; };

// pack 8 f32 -> one plain bf16 fragment (weights, init only — residuals dropped:
// R12/R15/R16 showed output absmax insensitive to precision down to bf16)
__device__ __forceinline__ bf16x8 pack8(const float* x) {
    FragU H;
    #pragma unroll
    for (int i = 0; i < 8; ++i) H.h[i] = bf2u(__float2bfloat16(x[i]));
    return H.f;
}

// plain bf16 quad pack (z and a operand paths)
__device__ __forceinline__ u16x4 packq(const f32x4& x) {
    u16x4 H;
    #pragma unroll
    for (int i = 0; i < 4; ++i) H[i] = bf2u(__float2bfloat16(x[i]));
    return H;
}

__device__ __forceinline__ bf16x8 ldb128(const unsigned short* base, int byteoff) {
    return *(const bf16x8*)((const char*)base + byteoff);
}
__device__ __forceinline__ void stb64(unsigned short* base, int byteoff, u16x4 v) {
    *(u16x4*)((char*)base + byteoff) = v;
}

__global__ __launch_bounds__(NT, 2)
void ode_mfma17(const float* __restrict__ z0, const float* __restrict__ t,
                const float* __restrict__ W1, const float* __restrict__ b1,
                const float* __restrict__ W2, const float* __restrict__ b2,
                float* __restrict__ out)
{
    // z and a: single plain-bf16 tiles; weights: plain bf16 fragments.
    // [batch_row][feature], byte-index XOR-swizzled by (row&7)<<4.
    __shared__ __align__(16) unsigned short zHs[ROWS * Dsz];
    __shared__ __align__(16) unsigned short aHs[ROWS * Hsz];
    __shared__ float ts[Tsz];

    const int tid  = threadIdx.x;
    const int lane = tid & 63;
    const int w    = tid >> 6;   // wave: layer1 h-cols 32w..+31, layer2 d-cols 16w..+15
    const int g    = lane >> 4;
    const int c    = lane & 15;  // batch row within tile
    const int r0   = blockIdx.x * ROWS;

    if (tid < Tsz) ts[tid] = t[tid];

    // ---- z master in registers: zreg[reg] = z[batch=c][d = 16w + 4g + reg] ----
    f32x4 zreg = *(const f32x4*)&z0[(r0 + c) * Dsz + 16*w + 4*g];

    // ---- W1^T A-fragments: lane holds W1T[h=16(2w+nt)+c][d=32kt+8g+i] ----
    bf16x8 w1t[2][2];   // [nt][kt]
    #pragma unroll
    for (int nt = 0; nt < 2; ++nt) {
        const int n = 32*w + 16*nt + c;
        #pragma unroll
        for (int kt = 0; kt < 2; ++kt) {
            float tmp[8];
            #pragma unroll
            for (int i = 0; i < 8; ++i) tmp[i] = W1[(32*kt + 8*g + i) * Hsz + n];
            w1t[nt][kt] = pack8(tmp);
        }
    }
    // ---- W2^T A-fragments: lane holds W2T[d=16w+c][h=32kt2+8g+i] ----
    bf16x8 w2t[4];      // [kt2]
    {
        const int n = 16*w + c;
        #pragma unroll
        for (int kt2 = 0; kt2 < 4; ++kt2) {
            float tmp[8];
            #pragma unroll
            for (int i = 0; i < 8; ++i) tmp[i] = W2[(32*kt2 + 8*g + i) * Dsz + n];
            w2t[kt2] = pack8(tmp);
        }
    }
    f32x4 b1v[2], b2v;
    #pragma unroll
    for (int nt = 0; nt < 2; ++nt)
        #pragma unroll
        for (int reg = 0; reg < 4; ++reg)
            b1v[nt][reg] = b1[16*(2*w + nt) + 4*g + reg];
    #pragma unroll
    for (int reg = 0; reg < 4; ++reg) b2v[reg] = b2[16*w + 4*g + reg];

    // ---- loop-invariant swizzled LDS byte offsets ----
    const int zw = (c*128 + (16*w + 4*g)*2) ^ ((c & 7) << 4);          // b64 write
    int zrd[2], aw[2], ard[4];
    #pragma unroll
    for (int kt = 0; kt < 2; ++kt)
        zrd[kt] = (c*128 + (32*kt + 8*g)*2) ^ ((c & 7) << 4);          // b128 read
    #pragma unroll
    for (int nt = 0; nt < 2; ++nt)
        aw[nt] = (c*256 + (32*w + 16*nt + 4*g)*2) ^ ((c & 7) << 4);    // b64 write
    #pragma unroll
    for (int kt2 = 0; kt2 < 4; ++kt2)
        ard[kt2] = (c*256 + (32*kt2 + 8*g)*2) ^ ((c & 7) << 4);        // b128 read

    auto z_to_lds = [&]() {
        stb64(zHs, zw, packq(zreg));     // one b64
    };

    z_to_lds();
    __syncthreads();

    const int n_steps = (int)ceilf(fabsf(ts[1] - ts[0]) / 0.05f);   // = 2 (exact in f32)

    for (int iv = 0; iv < Tsz - 1; ++iv) {
        const float h = (ts[iv + 1] - ts[iv]) / (float)n_steps;
        for (int s = 0; s < n_steps; ++s) {
            // ---- layer 1 (transposed): a^T = tanh(W1T @ bf16(z^T) + b1) ----
            bf16x8 zh0 = ldb128(zHs, zrd[0]), zh1 = ldb128(zHs, zrd[1]);
            #pragma unroll
            for (int nt = 0; nt < 2; ++nt) {
                f32x4 aA = b1v[nt];
                aA = MFMA(w1t[nt][0], zh0, aA);
                aA = MFMA(w1t[nt][1], zh1, aA);
                f32x4 tv;
                #pragma unroll
                for (int reg = 0; reg < 4; ++reg) tv[reg] = fast_tanh(aA[reg]);
                stb64(aHs, aw[nt], packq(tv));   // one b64 store
            }
            __syncthreads();
            // ---- layer 2 (transposed): dz^T = W2T @ bf16(a^T) + b2 ----
            bf16x8 ah0 = ldb128(aHs, ard[0]), ah1 = ldb128(aHs, ard[1]);
            bf16x8 ah2 = ldb128(aHs, ard[2]), ah3 = ldb128(aHs, ard[3]);
            f32x4 dA = b2v;
            f32x4 dB = {0,0,0,0};
            dA = MFMA(w2t[0], ah0, dA);
            dB = MFMA(w2t[1], ah1, dB);
            dA = MFMA(w2t[2], ah2, dA);
            dB = MFMA(w2t[3], ah3, dB);
            f32x4 dz = dA + dB;
            zreg += h * dz;
            z_to_lds();                  // 1 b64 write
            __syncthreads();
        }
    }

    // ---- write result (one dwordx4 per lane) ----
    *(f32x4*)&out[(r0 + c) * Dsz + 16*w + 4*g] = zreg;
}

extern "C" void kernel_launch(void* const* d_in, const int* in_sizes, int n_in,
                              void* d_out, int out_size, void* d_ws, size_t ws_size,
                              hipStream_t stream) {
    const float* z0 = (const float*)d_in[0];
    const float* t  = (const float*)d_in[1];
    const float* W1 = (const float*)d_in[2];
    const float* b1 = (const float*)d_in[3];
    const float* W2 = (const float*)d_in[4];
    const float* b2 = (const float*)d_in[5];
    float* out = (float*)d_out;
    (void)in_sizes; (void)n_in; (void)out_size; (void)d_ws; (void)ws_size;

    ode_mfma17<<<dim3(Bsz / ROWS), dim3(NT), 0, stream>>>(z0, t, W1, b1, W2, b2, out);
}